// Round 2
// baseline (213.746 us; speedup 1.0000x reference)
//
#include <hip/hip_runtime.h>
#include <stdint.h>

// ---------------------------------------------------------------------------
// TensorNet: fused encoder MLP (128->256->256->256, relu) over 32x4096 tokens,
// per-batch mean -> p = relu(m^2) -> decoder MLP (256->512->512->10).
// Inputs/outputs fp32 (per reference). Encoder via bf16 MFMA + fp32 accum;
// decoder pure fp32.
// ---------------------------------------------------------------------------

#define NIN   128
#define NHID  256
#define NDEC  512
#define NOUTC 10
#define BATCH 32
#define NTOK  4096
#define MTILE 64
#define TPB   64               // encoder blocks per batch (4096/64)
#define NBLK  (BATCH * TPB)    // 2048 encoder blocks
#define XPAD  136              // x-tile LDS row stride (bf16 elems)
#define HPAD  264              // h-tile LDS row stride (bf16 elems), 528B rows

typedef short bf16x8 __attribute__((ext_vector_type(8)));
typedef float floatx4 __attribute__((ext_vector_type(4)));

__device__ __forceinline__ uint16_t f2b(float f) {
  union { float f; uint32_t u; } v; v.f = f;
  uint32_t r = v.u + 0x7FFFu + ((v.u >> 16) & 1u);   // RNE
  return (uint16_t)(r >> 16);
}

// ---------------------------------------------------------------------------
// Pack W1/W2/W3 (fp32 [K][256] row-major) into bf16 MFMA-B-fragment order:
//   packed[((ct*KC + kc)*64 + lane)*8 + j] =
//       bf16( W[kc*32 + (lane>>4)*8 + j][ct*16 + (lane&15)] )
// so the encoder's b_frag load is one coalesced 16B global load per lane.
// Also zero-inits the msum accumulator (poisoned 0xAA by the harness).
// ---------------------------------------------------------------------------
__global__ __launch_bounds__(256) void pack_weights(
    const float* __restrict__ W1, const float* __restrict__ W2,
    const float* __restrict__ W3, uint16_t* __restrict__ out,
    float* __restrict__ msum) {
  int p = blockIdx.x * blockDim.x + threadIdx.x;
  if (p < BATCH * NHID) msum[p] = 0.f;
  const float* W; int K; int base;
  if (p < 32768)      { W = W1; K = NIN;  base = 0; }
  else if (p < 98304) { W = W2; K = NHID; base = 32768; p -= 32768; }
  else                { W = W3; K = NHID; base = 98304; p -= 98304; }
  int j    = p & 7;
  int lane = (p >> 3) & 63;
  int rest = p >> 9;
  int KC = K >> 5;               // K/32 k-chunks
  int kc = rest % KC;
  int ct = rest / KC;
  int n = ct * 16 + (lane & 15);
  int k = kc * 32 + ((lane >> 4) << 3) + j;
  out[base + (((ct * KC + kc) * 64 + lane) << 3) + j] = f2b(W[k * NHID + n]);
}

// ---------------------------------------------------------------------------
// Fused encoder. Block = 256 thr (4 waves), 64 tokens. Wave w owns output
// columns [64w, 64w+64): acc[4 row-tiles][4 col-tiles] of 16x16x32 bf16 MFMA.
// x tile staged fp32->bf16 into LDS (aliased with the h buffer); h1/h2 stay
// in LDS. Layer3 fused: bias+relu+column-sum -> atomicAdd into msum[b][col].
// ---------------------------------------------------------------------------
__global__ __launch_bounds__(256) void encoder(
    const float* __restrict__ x,        // [BATCH*NTOK][NIN] fp32
    const uint16_t* __restrict__ pW,    // packed bf16 weights
    const float* __restrict__ b1,
    const float* __restrict__ b2,
    const float* __restrict__ b3,
    float* __restrict__ msum) {         // [BATCH][NHID] fp32 accum
  __shared__ uint16_t Hs[MTILE * HPAD]; // 33792 B; x-tile aliases the front

  const int tid  = threadIdx.x;
  const int wave = tid >> 6;
  const int lane = tid & 63;
  const int l15  = lane & 15;
  const int q    = lane >> 4;
  const int tok0 = blockIdx.x * MTILE;
  const int colbase = wave * 64;
  const int ctg0 = colbase >> 4;

  const uint16_t* pW1 = pW;             // KC=4
  const uint16_t* pW2 = pW + 32768;     // KC=8
  const uint16_t* pW3 = pW + 98304;     // KC=8

  // ---- stage x tile: fp32 -> bf16, rows stride XPAD ----
  {
    const int row = tid >> 2;
    const int c0  = (tid & 3) * 32;
    const float* xr = x + (size_t)(tok0 + row) * NIN + c0;
    for (int i = 0; i < 8; ++i) {
      float4 v = *(const float4*)(xr + i * 4);
      ushort4 u;
      u.x = f2b(v.x); u.y = f2b(v.y); u.z = f2b(v.z); u.w = f2b(v.w);
      *(ushort4*)&Hs[row * XPAD + c0 + i * 4] = u;
    }
  }
  __syncthreads();

  floatx4 acc[4][4];

  // ---------------- layer 1: x @ W1 (K = 128) ----------------
  for (int rt = 0; rt < 4; ++rt)
    for (int ct = 0; ct < 4; ++ct)
      acc[rt][ct] = (floatx4){0.f, 0.f, 0.f, 0.f};
  for (int kc = 0; kc < 4; ++kc) {
    bf16x8 a[4], b[4];
    for (int rt = 0; rt < 4; ++rt)
      a[rt] = *(const bf16x8*)&Hs[(rt * 16 + l15) * XPAD + kc * 32 + q * 8];
    for (int ct = 0; ct < 4; ++ct)
      b[ct] = *(const bf16x8*)(pW1 + ((((ctg0 + ct) * 4 + kc) * 64 + lane) << 3));
    for (int rt = 0; rt < 4; ++rt)
      for (int ct = 0; ct < 4; ++ct)
        acc[rt][ct] = __builtin_amdgcn_mfma_f32_16x16x32_bf16(
            a[rt], b[ct], acc[rt][ct], 0, 0, 0);
  }
  __syncthreads();   // all x-tile reads done before h1 overwrites the region

  // bias + relu -> Hs (h1), rows stride HPAD
  for (int ct = 0; ct < 4; ++ct) {
    const int col = colbase + ct * 16 + l15;
    const float bias = b1[col];
    for (int rt = 0; rt < 4; ++rt)
      for (int r = 0; r < 4; ++r) {
        int row = rt * 16 + q * 4 + r;
        Hs[row * HPAD + col] = f2b(fmaxf(acc[rt][ct][r] + bias, 0.f));
      }
  }
  __syncthreads();

  // ---------------- layer 2: h1 @ W2 (K = 256) ----------------
  for (int rt = 0; rt < 4; ++rt)
    for (int ct = 0; ct < 4; ++ct)
      acc[rt][ct] = (floatx4){0.f, 0.f, 0.f, 0.f};
  for (int kc = 0; kc < 8; ++kc) {
    bf16x8 a[4], b[4];
    for (int rt = 0; rt < 4; ++rt)
      a[rt] = *(const bf16x8*)&Hs[(rt * 16 + l15) * HPAD + kc * 32 + q * 8];
    for (int ct = 0; ct < 4; ++ct)
      b[ct] = *(const bf16x8*)(pW2 + ((((ctg0 + ct) * 8 + kc) * 64 + lane) << 3));
    for (int rt = 0; rt < 4; ++rt)
      for (int ct = 0; ct < 4; ++ct)
        acc[rt][ct] = __builtin_amdgcn_mfma_f32_16x16x32_bf16(
            a[rt], b[ct], acc[rt][ct], 0, 0, 0);
  }
  __syncthreads();   // everyone done READING h1 before overwrite
  for (int ct = 0; ct < 4; ++ct) {
    const int col = colbase + ct * 16 + l15;
    const float bias = b2[col];
    for (int rt = 0; rt < 4; ++rt)
      for (int r = 0; r < 4; ++r) {
        int row = rt * 16 + q * 4 + r;
        Hs[row * HPAD + col] = f2b(fmaxf(acc[rt][ct][r] + bias, 0.f));
      }
  }
  __syncthreads();

  // ---------------- layer 3: h2 @ W3 (K = 256), fused mean-partial ----------
  for (int rt = 0; rt < 4; ++rt)
    for (int ct = 0; ct < 4; ++ct)
      acc[rt][ct] = (floatx4){0.f, 0.f, 0.f, 0.f};
  for (int kc = 0; kc < 8; ++kc) {
    bf16x8 a[4], b[4];
    for (int rt = 0; rt < 4; ++rt)
      a[rt] = *(const bf16x8*)&Hs[(rt * 16 + l15) * HPAD + kc * 32 + q * 8];
    for (int ct = 0; ct < 4; ++ct)
      b[ct] = *(const bf16x8*)(pW3 + ((((ctg0 + ct) * 8 + kc) * 64 + lane) << 3));
    for (int rt = 0; rt < 4; ++rt)
      for (int ct = 0; ct < 4; ++ct)
        acc[rt][ct] = __builtin_amdgcn_mfma_f32_16x16x32_bf16(
            a[rt], b[ct], acc[rt][ct], 0, 0, 0);
  }
  // bias + relu + column-sum over this block's 64 tokens
  const int batch = blockIdx.x >> 6;   // / TPB
  for (int ct = 0; ct < 4; ++ct) {
    const int col = colbase + ct * 16 + l15;
    const float bias = b3[col];
    float s = 0.f;
    for (int rt = 0; rt < 4; ++rt)
      for (int r = 0; r < 4; ++r)
        s += fmaxf(acc[rt][ct][r] + bias, 0.f);   // 16 rows (this lane's quad)
    s += __shfl_xor(s, 16, 64);                   // fold quads
    s += __shfl_xor(s, 32, 64);                   // all 64 rows
    if (q == 0)
      atomicAdd(&msum[batch * NHID + col], s);
  }
}

// ---------------------------------------------------------------------------
// Decoder: per batch, m = msum/NTOK -> p = relu(m^2) -> 3 fp32 layers.
// Tiny (25 MFLOP); scalar fp32, coalesced weight-column reads.
// ---------------------------------------------------------------------------
__global__ __launch_bounds__(256) void decoder(
    const float* __restrict__ msum,
    const float* __restrict__ D1, const float* __restrict__ c1,
    const float* __restrict__ D2, const float* __restrict__ c2,
    const float* __restrict__ D3, const float* __restrict__ c3,
    float* __restrict__ out) {
  __shared__ float p[NHID];
  __shared__ float d1[NDEC];
  __shared__ float d2[NDEC];
  const int b = blockIdx.x, t = threadIdx.x;

  {
    float m = msum[b * NHID + t] * (1.f / NTOK);
    p[t] = m * m;                        // relu(m^2) == m^2
  }
  __syncthreads();

  for (int jj = 0; jj < 2; ++jj) {
    int j = t + jj * 256;
    float s = c1[j];
    for (int n = 0; n < NHID; ++n) s += p[n] * D1[n * NDEC + j];
    d1[j] = fmaxf(s, 0.f);
  }
  __syncthreads();

  for (int jj = 0; jj < 2; ++jj) {
    int j = t + jj * 256;
    float s = c2[j];
    for (int n = 0; n < NDEC; ++n) s += d1[n] * D2[n * NDEC + j];
    d2[j] = fmaxf(s, 0.f);
  }
  __syncthreads();

  if (t < NOUTC) {
    float s = c3[t];
    for (int k = 0; k < NDEC; ++k) s += d2[k] * D3[k * NOUTC + t];
    out[b * NOUTC + t] = s;
  }
}

// ---------------------------------------------------------------------------
extern "C" void kernel_launch(void* const* d_in, const int* in_sizes, int n_in,
                              void* d_out, int out_size, void* d_ws, size_t ws_size,
                              hipStream_t stream) {
  const float* x  = (const float*)d_in[0];
  const float* W1 = (const float*)d_in[1];
  const float* b1 = (const float*)d_in[2];
  const float* W2 = (const float*)d_in[3];
  const float* b2 = (const float*)d_in[4];
  const float* W3 = (const float*)d_in[5];
  const float* b3 = (const float*)d_in[6];
  const float* D1 = (const float*)d_in[7];
  const float* c1 = (const float*)d_in[8];
  const float* D2 = (const float*)d_in[9];
  const float* c2 = (const float*)d_in[10];
  const float* D3 = (const float*)d_in[11];
  const float* c3 = (const float*)d_in[12];

  // ws layout: [0, 320KB) packed bf16 weights | [384KB, 416KB) msum fp32
  uint16_t* pW   = (uint16_t*)d_ws;
  float*    msum = (float*)((char*)d_ws + 384 * 1024);

  pack_weights<<<640, 256, 0, stream>>>(W1, W2, W3, pW, msum);
  encoder<<<NBLK, 256, 0, stream>>>(x, pW, b1, b2, b3, msum);
  decoder<<<BATCH, 256, 0, stream>>>(msum, D1, c1, D2, c2, D3, c3,
                                     (float*)d_out);
}

// Round 3
// 191.465 us; speedup vs baseline: 1.1164x; 1.1164x over previous
//
#include <hip/hip_runtime.h>
#include <stdint.h>

// ---------------------------------------------------------------------------
// TensorNet: fused encoder MLP (128->256->256->256, relu) over 32x4096 tokens,
// per-batch mean -> p = relu(m^2) -> decoder MLP (256->512->512->10).
// Inputs/outputs fp32. Encoder via bf16 MFMA + fp32 accum; decoder fp32,
// split into 3 launches for parallelism (R2: monolithic decoder was 75us
// at 1% occupancy — latency-bound on 32 blocks).
// ---------------------------------------------------------------------------

#define NIN   128
#define NHID  256
#define NDEC  512
#define NOUTC 10
#define BATCH 32
#define NTOK  4096
#define MTILE 64
#define TPB   64               // encoder blocks per batch (4096/64)
#define NBLK  (BATCH * TPB)    // 2048 encoder blocks
#define XPAD  136              // x-tile LDS row stride (bf16 elems)
#define HPAD  264              // h-tile LDS row stride (bf16 elems), 528B rows

typedef short bf16x8 __attribute__((ext_vector_type(8)));
typedef float floatx4 __attribute__((ext_vector_type(4)));

__device__ __forceinline__ uint16_t f2b(float f) {
  union { float f; uint32_t u; } v; v.f = f;
  uint32_t r = v.u + 0x7FFFu + ((v.u >> 16) & 1u);   // RNE
  return (uint16_t)(r >> 16);
}

// ---------------------------------------------------------------------------
// Pack W1/W2/W3 (fp32 [K][256] row-major) into bf16 MFMA-B-fragment order:
//   packed[((ct*KC + kc)*64 + lane)*8 + j] =
//       bf16( W[kc*32 + (lane>>4)*8 + j][ct*16 + (lane&15)] )
// Also zero-inits the msum accumulator (poisoned 0xAA by the harness).
// ---------------------------------------------------------------------------
__global__ __launch_bounds__(256) void pack_weights(
    const float* __restrict__ W1, const float* __restrict__ W2,
    const float* __restrict__ W3, uint16_t* __restrict__ out,
    float* __restrict__ msum) {
  int p = blockIdx.x * blockDim.x + threadIdx.x;
  if (p < BATCH * NHID) msum[p] = 0.f;
  const float* W; int K; int base;
  if (p < 32768)      { W = W1; K = NIN;  base = 0; }
  else if (p < 98304) { W = W2; K = NHID; base = 32768; p -= 32768; }
  else                { W = W3; K = NHID; base = 98304; p -= 98304; }
  int j    = p & 7;
  int lane = (p >> 3) & 63;
  int rest = p >> 9;
  int KC = K >> 5;               // K/32 k-chunks
  int kc = rest % KC;
  int ct = rest / KC;
  int n = ct * 16 + (lane & 15);
  int k = kc * 32 + ((lane >> 4) << 3) + j;
  out[base + (((ct * KC + kc) * 64 + lane) << 3) + j] = f2b(W[k * NHID + n]);
}

// ---------------------------------------------------------------------------
// Fused encoder. Block = 256 thr (4 waves), 64 tokens. Wave w owns output
// columns [64w, 64w+64): acc[4 row-tiles][4 col-tiles] of 16x16x32 bf16 MFMA.
// x tile staged fp32->bf16 into LDS; h1/h2 stay in LDS. Layer3 fused:
// bias+relu+column-sum -> atomicAdd into msum[b][col].
// ---------------------------------------------------------------------------
__global__ __launch_bounds__(256) void encoder(
    const float* __restrict__ x,        // [BATCH*NTOK][NIN] fp32
    const uint16_t* __restrict__ pW,    // packed bf16 weights
    const float* __restrict__ b1,
    const float* __restrict__ b2,
    const float* __restrict__ b3,
    float* __restrict__ msum) {         // [BATCH][NHID] fp32 accum
  __shared__ uint16_t Hs[MTILE * HPAD]; // 33792 B; x-tile aliases the front

  const int tid  = threadIdx.x;
  const int wave = tid >> 6;
  const int lane = tid & 63;
  const int l15  = lane & 15;
  const int q    = lane >> 4;
  const int tok0 = blockIdx.x * MTILE;
  const int colbase = wave * 64;
  const int ctg0 = colbase >> 4;

  const uint16_t* pW1 = pW;             // KC=4
  const uint16_t* pW2 = pW + 32768;     // KC=8
  const uint16_t* pW3 = pW + 98304;     // KC=8

  // ---- stage x tile: fp32 -> bf16, rows stride XPAD ----
  {
    const int row = tid >> 2;
    const int c0  = (tid & 3) * 32;
    const float* xr = x + (size_t)(tok0 + row) * NIN + c0;
    for (int i = 0; i < 8; ++i) {
      float4 v = *(const float4*)(xr + i * 4);
      ushort4 u;
      u.x = f2b(v.x); u.y = f2b(v.y); u.z = f2b(v.z); u.w = f2b(v.w);
      *(ushort4*)&Hs[row * XPAD + c0 + i * 4] = u;
    }
  }
  __syncthreads();

  floatx4 acc[4][4];

  // ---------------- layer 1: x @ W1 (K = 128) ----------------
  for (int rt = 0; rt < 4; ++rt)
    for (int ct = 0; ct < 4; ++ct)
      acc[rt][ct] = (floatx4){0.f, 0.f, 0.f, 0.f};
  for (int kc = 0; kc < 4; ++kc) {
    bf16x8 a[4], b[4];
    for (int rt = 0; rt < 4; ++rt)
      a[rt] = *(const bf16x8*)&Hs[(rt * 16 + l15) * XPAD + kc * 32 + q * 8];
    for (int ct = 0; ct < 4; ++ct)
      b[ct] = *(const bf16x8*)(pW1 + ((((ctg0 + ct) * 4 + kc) * 64 + lane) << 3));
    for (int rt = 0; rt < 4; ++rt)
      for (int ct = 0; ct < 4; ++ct)
        acc[rt][ct] = __builtin_amdgcn_mfma_f32_16x16x32_bf16(
            a[rt], b[ct], acc[rt][ct], 0, 0, 0);
  }
  __syncthreads();   // all x-tile reads done before h1 overwrites the region

  // bias + relu -> Hs (h1), rows stride HPAD
  for (int ct = 0; ct < 4; ++ct) {
    const int col = colbase + ct * 16 + l15;
    const float bias = b1[col];
    for (int rt = 0; rt < 4; ++rt)
      for (int r = 0; r < 4; ++r) {
        int row = rt * 16 + q * 4 + r;
        Hs[row * HPAD + col] = f2b(fmaxf(acc[rt][ct][r] + bias, 0.f));
      }
  }
  __syncthreads();

  // ---------------- layer 2: h1 @ W2 (K = 256) ----------------
  for (int rt = 0; rt < 4; ++rt)
    for (int ct = 0; ct < 4; ++ct)
      acc[rt][ct] = (floatx4){0.f, 0.f, 0.f, 0.f};
  for (int kc = 0; kc < 8; ++kc) {
    bf16x8 a[4], b[4];
    for (int rt = 0; rt < 4; ++rt)
      a[rt] = *(const bf16x8*)&Hs[(rt * 16 + l15) * HPAD + kc * 32 + q * 8];
    for (int ct = 0; ct < 4; ++ct)
      b[ct] = *(const bf16x8*)(pW2 + ((((ctg0 + ct) * 8 + kc) * 64 + lane) << 3));
    for (int rt = 0; rt < 4; ++rt)
      for (int ct = 0; ct < 4; ++ct)
        acc[rt][ct] = __builtin_amdgcn_mfma_f32_16x16x32_bf16(
            a[rt], b[ct], acc[rt][ct], 0, 0, 0);
  }
  __syncthreads();   // everyone done READING h1 before overwrite
  for (int ct = 0; ct < 4; ++ct) {
    const int col = colbase + ct * 16 + l15;
    const float bias = b2[col];
    for (int rt = 0; rt < 4; ++rt)
      for (int r = 0; r < 4; ++r) {
        int row = rt * 16 + q * 4 + r;
        Hs[row * HPAD + col] = f2b(fmaxf(acc[rt][ct][r] + bias, 0.f));
      }
  }
  __syncthreads();

  // ---------------- layer 3: h2 @ W3 (K = 256), fused mean-partial ----------
  for (int rt = 0; rt < 4; ++rt)
    for (int ct = 0; ct < 4; ++ct)
      acc[rt][ct] = (floatx4){0.f, 0.f, 0.f, 0.f};
  for (int kc = 0; kc < 8; ++kc) {
    bf16x8 a[4], b[4];
    for (int rt = 0; rt < 4; ++rt)
      a[rt] = *(const bf16x8*)&Hs[(rt * 16 + l15) * HPAD + kc * 32 + q * 8];
    for (int ct = 0; ct < 4; ++ct)
      b[ct] = *(const bf16x8*)(pW3 + ((((ctg0 + ct) * 8 + kc) * 64 + lane) << 3));
    for (int rt = 0; rt < 4; ++rt)
      for (int ct = 0; ct < 4; ++ct)
        acc[rt][ct] = __builtin_amdgcn_mfma_f32_16x16x32_bf16(
            a[rt], b[ct], acc[rt][ct], 0, 0, 0);
  }
  // bias + relu + column-sum over this block's 64 tokens
  const int batch = blockIdx.x >> 6;   // / TPB
  for (int ct = 0; ct < 4; ++ct) {
    const int col = colbase + ct * 16 + l15;
    const float bias = b3[col];
    float s = 0.f;
    for (int rt = 0; rt < 4; ++rt)
      for (int r = 0; r < 4; ++r)
        s += fmaxf(acc[rt][ct][r] + bias, 0.f);   // 16 rows (this lane's quad)
    s += __shfl_xor(s, 16, 64);                   // fold quads
    s += __shfl_xor(s, 32, 64);                   // all 64 rows
    if (q == 0)
      atomicAdd(&msum[batch * NHID + col], s);
  }
}

// ---------------------------------------------------------------------------
// Decoder, split for parallelism (R2: monolithic = 32 blocks, 75us).
// dec1: d1[b][j] = relu(c1[j] + sum_n p[b][n]*D1[n][j]),  p = (msum/NTOK)^2
//   grid (8,32): block = (64-col chunk, batch); 4 thr/col x 64-k partials.
// dec2: d2 = relu(c2 + d1 @ D2), K=512. grid (8,32); 4 thr/col x 128-k.
// dec3: out = c3 + d2 @ D3 ([512][10]). grid 32; 16 thr/col x 32-k.
// ---------------------------------------------------------------------------
__global__ __launch_bounds__(256) void dec1_kernel(
    const float* __restrict__ msum, const float* __restrict__ D1,
    const float* __restrict__ c1, float* __restrict__ d1out) {
  __shared__ float p[NHID];
  __shared__ float red[256];
  const int b = blockIdx.y, jc = blockIdx.x, t = threadIdx.x;
  {
    float m = msum[b * NHID + t] * (1.f / NTOK);
    p[t] = m * m;                       // relu(m^2) == m^2
  }
  __syncthreads();
  const int j  = jc * 64 + (t & 63);
  const int kc = t >> 6;                // 0..3, 64 k's each
  float s = 0.f;
  for (int k = kc * 64; k < kc * 64 + 64; ++k)
    s += p[k] * D1[k * NDEC + j];
  red[t] = s;
  __syncthreads();
  if (t < 64) {
    float v = red[t] + red[64 + t] + red[128 + t] + red[192 + t]
            + c1[jc * 64 + t];
    d1out[b * NDEC + jc * 64 + t] = fmaxf(v, 0.f);
  }
}

__global__ __launch_bounds__(256) void dec2_kernel(
    const float* __restrict__ d1, const float* __restrict__ D2,
    const float* __restrict__ c2, float* __restrict__ d2out) {
  __shared__ float h[NDEC];
  __shared__ float red[256];
  const int b = blockIdx.y, jc = blockIdx.x, t = threadIdx.x;
  h[t]       = d1[b * NDEC + t];
  h[t + 256] = d1[b * NDEC + t + 256];
  __syncthreads();
  const int j  = jc * 64 + (t & 63);
  const int kc = t >> 6;                // 0..3, 128 k's each
  float s = 0.f;
  for (int k = kc * 128; k < kc * 128 + 128; ++k)
    s += h[k] * D2[k * NDEC + j];
  red[t] = s;
  __syncthreads();
  if (t < 64) {
    float v = red[t] + red[64 + t] + red[128 + t] + red[192 + t]
            + c2[jc * 64 + t];
    d2out[b * NDEC + jc * 64 + t] = fmaxf(v, 0.f);
  }
}

__global__ __launch_bounds__(256) void dec3_kernel(
    const float* __restrict__ d2, const float* __restrict__ D3,
    const float* __restrict__ c3, float* __restrict__ out) {
  __shared__ float h[NDEC];
  __shared__ float red[256];
  const int b = blockIdx.x, t = threadIdx.x;
  h[t]       = d2[b * NDEC + t];
  h[t + 256] = d2[b * NDEC + t + 256];
  __syncthreads();
  const int j  = t & 15;                // 16 slots, NOUTC=10 valid
  const int kc = t >> 4;                // 16 chunks x 32 k's
  float s = 0.f;
  if (j < NOUTC)
    for (int k = kc * 32; k < kc * 32 + 32; ++k)
      s += h[k] * D3[k * NOUTC + j];
  red[t] = s;
  __syncthreads();
  if (t < NOUTC) {
    float v = c3[t];
    for (int i = 0; i < 16; ++i) v += red[i * 16 + t];
    out[b * NOUTC + t] = v;
  }
}

// ---------------------------------------------------------------------------
extern "C" void kernel_launch(void* const* d_in, const int* in_sizes, int n_in,
                              void* d_out, int out_size, void* d_ws, size_t ws_size,
                              hipStream_t stream) {
  const float* x  = (const float*)d_in[0];
  const float* W1 = (const float*)d_in[1];
  const float* b1 = (const float*)d_in[2];
  const float* W2 = (const float*)d_in[3];
  const float* b2 = (const float*)d_in[4];
  const float* W3 = (const float*)d_in[5];
  const float* b3 = (const float*)d_in[6];
  const float* D1 = (const float*)d_in[7];
  const float* c1 = (const float*)d_in[8];
  const float* D2 = (const float*)d_in[9];
  const float* c2 = (const float*)d_in[10];
  const float* D3 = (const float*)d_in[11];
  const float* c3 = (const float*)d_in[12];

  // ws layout: [0,320K) packed bf16 W | [384K,416K) msum | [448K,512K) d1 |
  //            [512K,576K) d2
  uint16_t* pW   = (uint16_t*)d_ws;
  float*    msum = (float*)((char*)d_ws + 384 * 1024);
  float*    d1s  = (float*)((char*)d_ws + 448 * 1024);
  float*    d2s  = (float*)((char*)d_ws + 512 * 1024);

  pack_weights<<<640, 256, 0, stream>>>(W1, W2, W3, pW, msum);
  encoder<<<NBLK, 256, 0, stream>>>(x, pW, b1, b2, b3, msum);
  dec1_kernel<<<dim3(8, BATCH), 256, 0, stream>>>(msum, D1, c1, d1s);
  dec2_kernel<<<dim3(8, BATCH), 256, 0, stream>>>(d1s, D2, c2, d2s);
  dec3_kernel<<<BATCH, 256, 0, stream>>>(d2s, D3, c3, (float*)d_out);
}